// Round 15
// baseline (131.883 us; speedup 1.0000x reference)
//
#include <hip/hip_runtime.h>
#include <hip/hip_fp16.h>

#define IN_DIM  16
#define HID_DIM 64
#define OUT_DIM 32

#define CAP   8192  // per-bucket capacity in gpart (mean 4096, +64 sigma)
#define EPB   3328  // edges per partA block (tile size — UNCHANGED from r6)
#define PAT   1024  // partA threads (r13: 4x TLP — measured 131.9 -> 128.9)
#define EPT   4     // ceil(EPB / PAT)
#define CONVB 16    // conv blocks (16*1024 = same conv thread count as 64*256)
#define PBT   1024  // partB threads (r6: 4x TLP + LDS-staged csr flush)

// ---------------------------------------------------------------------------
// Edge dtype: reference says int64, harness doc says int32. Detect inline:
// nonneg int64 < 2^31 has every odd 32-bit word == 0.
// ---------------------------------------------------------------------------
__device__ __forceinline__ int detect_is64(const void* edges) {
    const int* w = (const int*)edges;
    int is64 = 1;
    #pragma unroll
    for (int i = 0; i < 16; ++i) is64 &= (w[2 * i + 1] == 0);
    return is64;
}

__device__ __forceinline__ long long edge_at(const void* edges, int is64, long long i) {
    if (is64) return ((const long long*)edges)[i];
    return (long long)((const int*)edges)[i];
}

// accumulate 16 channels (two uint4 of fp16) with weight w (r15: agg2 remap)
#define ACC16(w, ra, rb) { \
    const __half2* hpa_ = (const __half2*)&(ra); \
    const __half2* hpb_ = (const __half2*)&(rb); \
    _Pragma("unroll") \
    for (int c_ = 0; c_ < 4; ++c_) { \
        float2 fa_ = __half22float2(hpa_[c_]); \
        float2 fb_ = __half22float2(hpb_[c_]); \
        acc[c_ * 2]         += (w) * fa_.x; \
        acc[c_ * 2 + 1]     += (w) * fa_.y; \
        acc[8 + c_ * 2]     += (w) * fb_.x; \
        acc[8 + c_ * 2 + 1] += (w) * fb_.y; } }

// ---------------------------------------------------------------------------
// partA (r13: 1024-thread blocks — measured −3.0us vs 256-thread).
// Same 3328-edge tile, same flush scheme, same atomic counts as r6; only the
// block is 4x wider (~16 waves/CU) to hide edge-load + LDS-phase latency.
// Blocks >= nblkA convert x -> fp16 (ride-along). Entry: src|((dst&255)<<16).
// ---------------------------------------------------------------------------
__global__ __launch_bounds__(PAT) void k_partA(const void* edges, int* gcur,
                                               unsigned int* gpart, int nbuk, long long E,
                                               const float* __restrict__ x,
                                               __half* __restrict__ xh,
                                               long long xElems, int nblkA) {
    if (blockIdx.x >= nblkA) {
        // x -> fp16 conversion, grid-stride, coalesced
        const float4* x4 = (const float4*)x;
        uint2* outp = (uint2*)xh;
        long long n4 = xElems >> 2;
        for (long long i = (long long)(blockIdx.x - nblkA) * PAT + threadIdx.x;
             i < n4; i += (long long)CONVB * PAT) {
            float4 v = x4[i];
            __half2 a = __floats2half2_rn(v.x, v.y);
            __half2 b = __floats2half2_rn(v.z, v.w);
            outp[i] = make_uint2(*(unsigned int*)&a, *(unsigned int*)&b);
        }
        return;
    }

    __shared__ unsigned int staged[EPB];     // 13 KB
    __shared__ int hcnt[256], hoff[256], hcur[256];
    __shared__ int wsum[4];
    __shared__ int s64s;
    int t = threadIdx.x;
    int lane = t & 63, wv = t >> 6;
    if (t == 0) s64s = detect_is64(edges);
    if (t < 256) hcnt[t] = 0;
    __syncthreads();
    int is64 = s64s;

    long long e0 = (long long)blockIdx.x * EPB;
    unsigned int rs[EPT], rd[EPT];
    #pragma unroll
    for (int k = 0; k < EPT; ++k) {
        int el = t + k * PAT;
        long long e = e0 + el;
        if (el < EPB && e < E) {
            rs[k] = (unsigned int)edge_at(edges, is64, e);
            rd[k] = (unsigned int)edge_at(edges, is64, E + e);
            atomicAdd(&hcnt[rd[k] >> 8], 1);
        } else {
            rd[k] = 0xffffffffu;             // sentinel: invalid slot
        }
    }
    __syncthreads();

    // scan of hcnt -> exclusive offsets (first 256 threads own bins)
    int v = (t < 256) ? hcnt[t] : 0;
    int s = v;
    #pragma unroll
    for (int d = 1; d < 64; d <<= 1) {
        int u = __shfl_up(s, d, 64);
        if (lane >= d) s += u;
    }
    if (t < 256 && lane == 63) wsum[wv] = s;
    __syncthreads();
    if (t < 256) {
        int add = 0;
        #pragma unroll
        for (int i = 0; i < 4; ++i)
            if (i < wv) add += wsum[i];
        int excl = (s + add) - v;
        hoff[t] = excl;
        hcur[t] = excl;
    }
    __syncthreads();

    #pragma unroll
    for (int k = 0; k < EPT; ++k) {
        if (rd[k] != 0xffffffffu) {
            int p = atomicAdd(&hcur[rd[k] >> 8], 1);
            staged[p] = rs[k] | ((rd[k] & 255u) << 16);
        }
    }
    __syncthreads();

    // serial per-thread flush (measured better than wave-cooperative)
    if (t < nbuk) {
        int c = hcnt[t];
        if (c > 0) {
            int base = atomicAdd(&gcur[t], c);
            int o = hoff[t];
            for (int k = 0; k < c; ++k) {
                int idx = base + k;
                if (idx < CAP) gpart[(size_t)t * CAP + idx] = staged[o + k];
            }
        }
    }
}

// ---------------------------------------------------------------------------
// partB (r6 form): one 1024-thread block per bucket; LDS-staged csr flush.
// ---------------------------------------------------------------------------
__global__ __launch_bounds__(PBT) void k_partB(const int* __restrict__ gcur,
                                               const unsigned int* __restrict__ gpart,
                                               unsigned short* __restrict__ csr,
                                               int* __restrict__ offs,
                                               float* __restrict__ dinv,
                                               int nbuk, int N) {
    __shared__ unsigned int   ebuf[CAP];     // 32 KB
    __shared__ unsigned short sbuf[CAP];     // 16 KB (staging for csr)
    __shared__ int bscan[256];
    __shared__ int hcnt[256], hcur[256];
    __shared__ int wsum[4];
    int t = threadIdx.x;
    int lane = t & 63, wv = t >> 6;
    int b = blockIdx.x;

    // ---- bucket-count scan (first 256 threads own slots) ----
    int bc = (t < 256 && t < nbuk) ? min(gcur[t], CAP) : 0;
    if (t < 256) hcnt[t] = 0;
    int s = bc;
    #pragma unroll
    for (int d = 1; d < 64; d <<= 1) {
        int u = __shfl_up(s, d, 64);
        if (lane >= d) s += u;
    }
    if (t < 256 && lane == 63) wsum[wv] = s;
    __syncthreads();
    if (t < 256) {
        int add = 0;
        #pragma unroll
        for (int i = 0; i < 4; ++i)
            if (i < wv) add += wsum[i];
        bscan[t] = s + add;
    }
    __syncthreads();
    int base = (b == 0) ? 0 : bscan[b - 1];
    int cnt  = bscan[b] - base;

    // ---- load bucket + fine histogram ----
    for (int i = t; i < cnt; i += PBT) ebuf[i] = gpart[(size_t)b * CAP + i];
    __syncthreads();
    for (int i = t; i < cnt; i += PBT) atomicAdd(&hcnt[(ebuf[i] >> 16) & 255u], 1);
    __syncthreads();

    // ---- fine-histogram scan (first 256 threads) ----
    int v = (t < 256) ? hcnt[t] : 0;
    s = v;
    #pragma unroll
    for (int d = 1; d < 64; d <<= 1) {
        int u = __shfl_up(s, d, 64);
        if (lane >= d) s += u;
    }
    if (t < 256 && lane == 63) wsum[wv] = s;   // wsum reuse: barrier-separated
    __syncthreads();
    if (t < 256) {
        int add = 0;
        #pragma unroll
        for (int i = 0; i < 4; ++i)
            if (i < wv) add += wsum[i];
        int excl = (s + add) - v;
        hcur[t] = excl;
        int node = b * 256 + t;
        if (node < N) {
            offs[node] = base + excl;
            dinv[node] = rsqrtf((float)v + 1.0f);
        }
    }
    if (b == nbuk - 1 && t == 0) offs[N] = bscan[nbuk - 1];
    __syncthreads();

    // ---- scatter u16 src into LDS staging (random LDS, cheap) ----
    for (int i = t; i < cnt; i += PBT) {
        unsigned int e = ebuf[i];
        int p = atomicAdd(&hcur[(e >> 16) & 255u], 1);
        sbuf[p] = (unsigned short)(e & 0xffffu);
    }
    __syncthreads();
    // ---- coalesced flush to global csr ----
    for (int i = t; i < cnt; i += PBT) csr[base + i] = sbuf[i];
}

// ---------------------------------------------------------------------------
// Fused layer-1 gather + dense GEMMs (r3/r6 form — measured in 128.9 config).
// ---------------------------------------------------------------------------
#define ASTR 17   // 16 + 1 pad: nodes land in distinct banks in GEMM1
#define H1S  68   // 64 + 4 pad, keeps float4 chunks 16B-aligned
__global__ __launch_bounds__(256, 6) void k_agg1g(
    const __half* __restrict__ xh, const float* __restrict__ dinv,
    const int* __restrict__ offs, const unsigned short* __restrict__ csr,
    const float* __restrict__ W1, const float* __restrict__ b1,
    const float* __restrict__ W2, __half* __restrict__ h2, int N)
{
    __shared__ __align__(16) float W1s[IN_DIM * HID_DIM];    // 4 KB
    __shared__ __align__(16) float W2s[HID_DIM * OUT_DIM];   // 8 KB
    __shared__ float b1s[HID_DIM];
    __shared__ __align__(16) float aggs[16 * ASTR];          // 1.1 KB
    __shared__ __align__(16) float h1s[16 * H1S];            // 4.3 KB

    int tid = threadIdx.x;
    int lane = tid & 63;
    int g = lane >> 4, sub = lane & 15;
    int comp = sub >> 3;     // 0..1 : which 8-channel (16 B) half of the row
    int way  = sub & 7;      // 0..7 edge ways
    int nl   = (tid >> 6) * 4 + g;          // node_local 0..15
    int node = blockIdx.x * 16 + nl;

    // head of the dependent chain FIRST: offs/dinv for this node
    float di = 0.f;
    int start = 0, end = 0;
    if (node < N) {
        di = dinv[node];
        start = offs[node];
        end = offs[node + 1];
    }

    // stage weights (independent loads — fill the latency shadow)
    for (int i = tid; i < IN_DIM * HID_DIM; i += 256) W1s[i] = W1[i];
    for (int i = tid; i < HID_DIM * OUT_DIM; i += 256) W2s[i] = W2[i];
    if (tid < HID_DIM) b1s[tid] = b1[tid];

    // ---- gather phase ----
    float acc[8] = {0.f, 0.f, 0.f, 0.f, 0.f, 0.f, 0.f, 0.f};
    if (node < N) {                          // predicated, NOT return: barriers below
        const uint4* x2 = (const uint4*)xh;  // [N][2] uint4
        if (way == 0) {
            uint4 r = x2[(size_t)node * 2 + comp];
            const __half2* hp = (const __half2*)&r;
            #pragma unroll
            for (int c = 0; c < 4; ++c) {
                float2 f = __half22float2(hp[c]);
                acc[c * 2]     = di * f.x;
                acc[c * 2 + 1] = di * f.y;
            }
        }
        int j = start + way;
        for (; j + 8 < end; j += 16) {
            int s0 = csr[j], s1 = csr[j + 8];
            float w0 = dinv[s0], w1 = dinv[s1];
            uint4 r0 = x2[(size_t)s0 * 2 + comp];
            uint4 r1 = x2[(size_t)s1 * 2 + comp];
            const __half2* hp0 = (const __half2*)&r0;
            const __half2* hp1 = (const __half2*)&r1;
            #pragma unroll
            for (int c = 0; c < 4; ++c) {
                float2 f0 = __half22float2(hp0[c]);
                float2 f1 = __half22float2(hp1[c]);
                acc[c * 2]     += w0 * f0.x + w1 * f1.x;
                acc[c * 2 + 1] += w0 * f0.y + w1 * f1.y;
            }
        }
        if (j < end) {
            int s = csr[j];
            float w = dinv[s];
            uint4 r = x2[(size_t)s * 2 + comp];
            const __half2* hp = (const __half2*)&r;
            #pragma unroll
            for (int c = 0; c < 4; ++c) {
                float2 f = __half22float2(hp[c]);
                acc[c * 2]     += w * f.x;
                acc[c * 2 + 1] += w * f.y;
            }
        }
        // xor-reduce over way bits (lanes in each xor group share `node`)
        #pragma unroll
        for (int m = 1; m <= 4; m <<= 1) {
            #pragma unroll
            for (int c = 0; c < 8; ++c) acc[c] += __shfl_xor(acc[c], m, 64);
        }
    }
    if (way == 0) {   // both comps write; invalid nodes write zeros (di=0)
        #pragma unroll
        for (int c = 0; c < 8; ++c) aggs[nl * ASTR + comp * 8 + c] = di * acc[c];
    }
    __syncthreads();

    // ---- GEMM phase: thread = (node nl2, quarter-col q) ----
    int nl2 = tid >> 4, q = tid & 15;

    // GEMM1 + ReLU: hidden cols q*4 .. q*4+3
    float a1[4];
    #pragma unroll
    for (int c = 0; c < 4; ++c) a1[c] = b1s[q * 4 + c];
    #pragma unroll
    for (int k = 0; k < IN_DIM; ++k) {
        float a = aggs[nl2 * ASTR + k];
        float4 w = *(const float4*)&W1s[k * HID_DIM + q * 4];
        a1[0] += a * w.x; a1[1] += a * w.y; a1[2] += a * w.z; a1[3] += a * w.w;
    }
    *(float4*)&h1s[nl2 * H1S + q * 4] =
        make_float4(fmaxf(a1[0], 0.f), fmaxf(a1[1], 0.f),
                    fmaxf(a1[2], 0.f), fmaxf(a1[3], 0.f));
    __syncthreads();

    // GEMM2: out cols q*2, q*2+1 -> fp16 (one uint per thread; 16 consecutive
    // uints per node = 64 B coalesced store)
    float a2x = 0.f, a2y = 0.f;
    const float4* h1row = (const float4*)&h1s[nl2 * H1S];
    #pragma unroll
    for (int k4 = 0; k4 < 16; ++k4) {
        float4 hv = h1row[k4];
        const float* wb = &W2s[(k4 * 4) * OUT_DIM + q * 2];
        float2 w0 = *(const float2*)(wb);
        float2 w1 = *(const float2*)(wb + OUT_DIM);
        float2 w2 = *(const float2*)(wb + 2 * OUT_DIM);
        float2 w3 = *(const float2*)(wb + 3 * OUT_DIM);
        a2x += hv.x * w0.x + hv.y * w1.x + hv.z * w2.x + hv.w * w3.x;
        a2y += hv.x * w0.y + hv.y * w1.y + hv.z * w2.y + hv.w * w3.y;
    }
    int gn = blockIdx.x * 16 + nl2;
    if (gn < N) {
        __half2 p = __floats2half2_rn(a2x, a2y);
        ((unsigned int*)h2)[(size_t)gn * 16 + q] = *(unsigned int*)&p;
    }
}

// ---------------------------------------------------------------------------
// Layer-2 gather (r15 remap): 4 nodes per wave; each node owns 16 lanes =
// 2 comps (32 B half of the 64 B row, two uint4 per source) x 8 edge-ways.
// Halves the per-way serial edge count (4.3 -> 2.1 -> ~1 chained iteration)
// vs the 4x4 layout, with NO speculative loads (r4's failure was the agg1
// 3-slot preload, co-mingled with this remap — here it's isolated).
// Reduction = 3 xor steps over way bits; acc[16] channels per lane.
// out[i][c] = b2[c] + di*(di*h2[i][c] + sum_s dinv_s*h2[s][c])
// ---------------------------------------------------------------------------
__global__ __launch_bounds__(256, 6) void k_agg2(
    const __half* __restrict__ h2, const float* __restrict__ dinv,
    const int* __restrict__ offs, const unsigned short* __restrict__ csr,
    const float* __restrict__ b2, float* __restrict__ out, int N)
{
    int gtid = blockIdx.x * 256 + threadIdx.x;
    int lane = gtid & 63;
    int g = lane >> 4, sub = lane & 15;
    int comp = sub >> 3;     // 0..1 : which 32 B half of the 64 B row
    int way  = sub & 7;      // 0..7 edge ways
    int node = (gtid >> 6) * 4 + g;
    if (node >= N) return;   // no barriers here -> early return OK
    const uint4* h24 = (const uint4*)h2;
    float di = dinv[node];
    int start = offs[node], end = offs[node + 1];

    float acc[16];
    #pragma unroll
    for (int c = 0; c < 16; ++c) acc[c] = 0.f;

    if (way == 0) {          // self term, weight di
        uint4 rsa = h24[(size_t)node * 4 + comp * 2];
        uint4 rsb = h24[(size_t)node * 4 + comp * 2 + 1];
        ACC16(di, rsa, rsb);
    }
    int j = start + way;
    for (; j + 8 < end; j += 16) {
        int s0 = csr[j], s1 = csr[j + 8];
        float w0 = dinv[s0], w1 = dinv[s1];
        uint4 ra0 = h24[(size_t)s0 * 4 + comp * 2];
        uint4 rb0 = h24[(size_t)s0 * 4 + comp * 2 + 1];
        uint4 ra1 = h24[(size_t)s1 * 4 + comp * 2];
        uint4 rb1 = h24[(size_t)s1 * 4 + comp * 2 + 1];
        ACC16(w0, ra0, rb0);
        ACC16(w1, ra1, rb1);
    }
    if (j < end) {
        int s = csr[j];
        float w = dinv[s];
        uint4 ra = h24[(size_t)s * 4 + comp * 2];
        uint4 rb = h24[(size_t)s * 4 + comp * 2 + 1];
        ACC16(w, ra, rb);
    }

    #pragma unroll
    for (int m = 1; m <= 4; m <<= 1) {
        #pragma unroll
        for (int c = 0; c < 16; ++c) acc[c] += __shfl_xor(acc[c], m, 64);
    }
    if (way == 0) {
        const float4* b24 = (const float4*)b2;
        float4* out4 = (float4*)out;
        #pragma unroll
        for (int k = 0; k < 4; ++k) {
            float4 bb = b24[comp * 4 + k];
            out4[(size_t)node * 8 + comp * 4 + k] =
                make_float4(di * acc[k * 4 + 0] + bb.x,
                            di * acc[k * 4 + 1] + bb.y,
                            di * acc[k * 4 + 2] + bb.z,
                            di * acc[k * 4 + 3] + bb.w);
        }
    }
}

extern "C" void kernel_launch(void* const* d_in, const int* in_sizes, int n_in,
                              void* d_out, int out_size, void* d_ws, size_t ws_size,
                              hipStream_t stream) {
    const float* x     = (const float*)d_in[0];
    const void*  edges = d_in[1];
    const float* W1    = (const float*)d_in[2];
    const float* b1    = (const float*)d_in[3];
    const float* W2    = (const float*)d_in[4];
    const float* b2    = (const float*)d_in[5];
    float* out = (float*)d_out;

    const int       N = in_sizes[0] / IN_DIM;   // 50000 (fits u16)
    const long long E = in_sizes[1] / 2;        // 800000
    const int    NBUK = (N + 255) >> 8;         // 196 coarse buckets (<=256)
    const int   NBLKA = (int)((E + EPB - 1) / EPB);

    // ws layout: csr [E u16, pad to 16B] | gpart [NBUK*CAP u32] | xh [16N half]
    // | h2 [32N half] | dinv [N f] | offs [N+1] | gcur [NBUK]
    unsigned short* csr   = (unsigned short*)d_ws;
    unsigned int*   gpart = (unsigned int*)(csr + ((E + 7) & ~7LL));
    __half* xh       = (__half*)(gpart + (size_t)NBUK * CAP);
    __half* h2       = (__half*)(xh + (size_t)IN_DIM * N);
    float*  dinv     = (float*)(h2 + (size_t)OUT_DIM * N);
    int*    offs     = (int*)(dinv + N);
    int*    gcur     = offs + N + 1;

    const int B = 256;
    hipMemsetAsync(gcur, 0, (size_t)NBUK * sizeof(int), stream);
    k_partA<<<NBLKA + CONVB, PAT, 0, stream>>>(edges, gcur, gpart, NBUK, E,
                                               x, xh, (long long)N * IN_DIM, NBLKA);
    k_partB<<<NBUK, PBT, 0, stream>>>(gcur, gpart, csr, offs, dinv, NBUK, N);

    // fused gather + GEMMs: 16 nodes per 256-thread block
    k_agg1g<<<(N + 15) / 16, B, 0, stream>>>(xh, dinv, offs, csr,
                                             W1, b1, W2, h2, N);
    k_agg2<<<(N + 15) / 16, B, 0, stream>>>(h2, dinv, offs, csr, b2, out, N);
}

// Round 16
// 128.158 us; speedup vs baseline: 1.0291x; 1.0291x over previous
//
#include <hip/hip_runtime.h>
#include <hip/hip_fp16.h>

#define IN_DIM  16
#define HID_DIM 64
#define OUT_DIM 32

#define CAP   8192  // per-bucket capacity in gpart (mean 4096, +64 sigma)
#define EPB   3328  // edges per partA block (tile size — UNCHANGED from r6)
#define PAT   1024  // partA threads (r13: 4x TLP — measured 131.9 -> 128.9)
#define EPT   4     // ceil(EPB / PAT)
#define CONVB 16    // conv blocks (16*1024 = same conv thread count as 64*256)
#define PBT   1024  // partB threads (r6: 4x TLP + LDS-staged csr flush)

// ---------------------------------------------------------------------------
// Edge dtype: reference says int64, harness doc says int32. Detect inline:
// nonneg int64 < 2^31 has every odd 32-bit word == 0.
// ---------------------------------------------------------------------------
__device__ __forceinline__ int detect_is64(const void* edges) {
    const int* w = (const int*)edges;
    int is64 = 1;
    #pragma unroll
    for (int i = 0; i < 16; ++i) is64 &= (w[2 * i + 1] == 0);
    return is64;
}

__device__ __forceinline__ long long edge_at(const void* edges, int is64, long long i) {
    if (is64) return ((const long long*)edges)[i];
    return (long long)((const int*)edges)[i];
}

// ---------------------------------------------------------------------------
// partA (r13: 1024-thread blocks — measured −3.0us vs 256-thread).
// Same 3328-edge tile, same flush scheme, same atomic counts as r6; only the
// block is 4x wider (~16 waves/CU) to hide edge-load + LDS-phase latency.
// Blocks >= nblkA convert x -> fp16 (ride-along). Entry: src|((dst&255)<<16).
// ---------------------------------------------------------------------------
__global__ __launch_bounds__(PAT) void k_partA(const void* edges, int* gcur,
                                               unsigned int* gpart, int nbuk, long long E,
                                               const float* __restrict__ x,
                                               __half* __restrict__ xh,
                                               long long xElems, int nblkA) {
    if (blockIdx.x >= nblkA) {
        // x -> fp16 conversion, grid-stride, coalesced
        const float4* x4 = (const float4*)x;
        uint2* outp = (uint2*)xh;
        long long n4 = xElems >> 2;
        for (long long i = (long long)(blockIdx.x - nblkA) * PAT + threadIdx.x;
             i < n4; i += (long long)CONVB * PAT) {
            float4 v = x4[i];
            __half2 a = __floats2half2_rn(v.x, v.y);
            __half2 b = __floats2half2_rn(v.z, v.w);
            outp[i] = make_uint2(*(unsigned int*)&a, *(unsigned int*)&b);
        }
        return;
    }

    __shared__ unsigned int staged[EPB];     // 13 KB
    __shared__ int hcnt[256], hoff[256], hcur[256];
    __shared__ int wsum[4];
    __shared__ int s64s;
    int t = threadIdx.x;
    int lane = t & 63, wv = t >> 6;
    if (t == 0) s64s = detect_is64(edges);
    if (t < 256) hcnt[t] = 0;
    __syncthreads();
    int is64 = s64s;

    long long e0 = (long long)blockIdx.x * EPB;
    unsigned int rs[EPT], rd[EPT];
    #pragma unroll
    for (int k = 0; k < EPT; ++k) {
        int el = t + k * PAT;
        long long e = e0 + el;
        if (el < EPB && e < E) {
            rs[k] = (unsigned int)edge_at(edges, is64, e);
            rd[k] = (unsigned int)edge_at(edges, is64, E + e);
            atomicAdd(&hcnt[rd[k] >> 8], 1);
        } else {
            rd[k] = 0xffffffffu;             // sentinel: invalid slot
        }
    }
    __syncthreads();

    // scan of hcnt -> exclusive offsets (first 256 threads own bins)
    int v = (t < 256) ? hcnt[t] : 0;
    int s = v;
    #pragma unroll
    for (int d = 1; d < 64; d <<= 1) {
        int u = __shfl_up(s, d, 64);
        if (lane >= d) s += u;
    }
    if (t < 256 && lane == 63) wsum[wv] = s;
    __syncthreads();
    if (t < 256) {
        int add = 0;
        #pragma unroll
        for (int i = 0; i < 4; ++i)
            if (i < wv) add += wsum[i];
        int excl = (s + add) - v;
        hoff[t] = excl;
        hcur[t] = excl;
    }
    __syncthreads();

    #pragma unroll
    for (int k = 0; k < EPT; ++k) {
        if (rd[k] != 0xffffffffu) {
            int p = atomicAdd(&hcur[rd[k] >> 8], 1);
            staged[p] = rs[k] | ((rd[k] & 255u) << 16);
        }
    }
    __syncthreads();

    // serial per-thread flush (measured better than wave-cooperative)
    if (t < nbuk) {
        int c = hcnt[t];
        if (c > 0) {
            int base = atomicAdd(&gcur[t], c);
            int o = hoff[t];
            for (int k = 0; k < c; ++k) {
                int idx = base + k;
                if (idx < CAP) gpart[(size_t)t * CAP + idx] = staged[o + k];
            }
        }
    }
}

// ---------------------------------------------------------------------------
// partB (r6 form): one 1024-thread block per bucket; LDS-staged csr flush.
// ---------------------------------------------------------------------------
__global__ __launch_bounds__(PBT) void k_partB(const int* __restrict__ gcur,
                                               const unsigned int* __restrict__ gpart,
                                               unsigned short* __restrict__ csr,
                                               int* __restrict__ offs,
                                               float* __restrict__ dinv,
                                               int nbuk, int N) {
    __shared__ unsigned int   ebuf[CAP];     // 32 KB
    __shared__ unsigned short sbuf[CAP];     // 16 KB (staging for csr)
    __shared__ int bscan[256];
    __shared__ int hcnt[256], hcur[256];
    __shared__ int wsum[4];
    int t = threadIdx.x;
    int lane = t & 63, wv = t >> 6;
    int b = blockIdx.x;

    // ---- bucket-count scan (first 256 threads own slots) ----
    int bc = (t < 256 && t < nbuk) ? min(gcur[t], CAP) : 0;
    if (t < 256) hcnt[t] = 0;
    int s = bc;
    #pragma unroll
    for (int d = 1; d < 64; d <<= 1) {
        int u = __shfl_up(s, d, 64);
        if (lane >= d) s += u;
    }
    if (t < 256 && lane == 63) wsum[wv] = s;
    __syncthreads();
    if (t < 256) {
        int add = 0;
        #pragma unroll
        for (int i = 0; i < 4; ++i)
            if (i < wv) add += wsum[i];
        bscan[t] = s + add;
    }
    __syncthreads();
    int base = (b == 0) ? 0 : bscan[b - 1];
    int cnt  = bscan[b] - base;

    // ---- load bucket + fine histogram ----
    for (int i = t; i < cnt; i += PBT) ebuf[i] = gpart[(size_t)b * CAP + i];
    __syncthreads();
    for (int i = t; i < cnt; i += PBT) atomicAdd(&hcnt[(ebuf[i] >> 16) & 255u], 1);
    __syncthreads();

    // ---- fine-histogram scan (first 256 threads) ----
    int v = (t < 256) ? hcnt[t] : 0;
    s = v;
    #pragma unroll
    for (int d = 1; d < 64; d <<= 1) {
        int u = __shfl_up(s, d, 64);
        if (lane >= d) s += u;
    }
    if (t < 256 && lane == 63) wsum[wv] = s;   // wsum reuse: barrier-separated
    __syncthreads();
    if (t < 256) {
        int add = 0;
        #pragma unroll
        for (int i = 0; i < 4; ++i)
            if (i < wv) add += wsum[i];
        int excl = (s + add) - v;
        hcur[t] = excl;
        int node = b * 256 + t;
        if (node < N) {
            offs[node] = base + excl;
            dinv[node] = rsqrtf((float)v + 1.0f);
        }
    }
    if (b == nbuk - 1 && t == 0) offs[N] = bscan[nbuk - 1];
    __syncthreads();

    // ---- scatter u16 src into LDS staging (random LDS, cheap) ----
    for (int i = t; i < cnt; i += PBT) {
        unsigned int e = ebuf[i];
        int p = atomicAdd(&hcur[(e >> 16) & 255u], 1);
        sbuf[p] = (unsigned short)(e & 0xffffu);
    }
    __syncthreads();
    // ---- coalesced flush to global csr ----
    for (int i = t; i < cnt; i += PBT) csr[base + i] = sbuf[i];
}

// ---------------------------------------------------------------------------
// Fused layer-1 gather + dense GEMMs (r3/r6 form — measured in 128.9 config).
// ---------------------------------------------------------------------------
#define ASTR 17   // 16 + 1 pad: nodes land in distinct banks in GEMM1
#define H1S  68   // 64 + 4 pad, keeps float4 chunks 16B-aligned
__global__ __launch_bounds__(256, 6) void k_agg1g(
    const __half* __restrict__ xh, const float* __restrict__ dinv,
    const int* __restrict__ offs, const unsigned short* __restrict__ csr,
    const float* __restrict__ W1, const float* __restrict__ b1,
    const float* __restrict__ W2, __half* __restrict__ h2, int N)
{
    __shared__ __align__(16) float W1s[IN_DIM * HID_DIM];    // 4 KB
    __shared__ __align__(16) float W2s[HID_DIM * OUT_DIM];   // 8 KB
    __shared__ float b1s[HID_DIM];
    __shared__ __align__(16) float aggs[16 * ASTR];          // 1.1 KB
    __shared__ __align__(16) float h1s[16 * H1S];            // 4.3 KB

    int tid = threadIdx.x;
    int lane = tid & 63;
    int g = lane >> 4, sub = lane & 15;
    int comp = sub >> 3;     // 0..1 : which 8-channel (16 B) half of the row
    int way  = sub & 7;      // 0..7 edge ways
    int nl   = (tid >> 6) * 4 + g;          // node_local 0..15
    int node = blockIdx.x * 16 + nl;

    // head of the dependent chain FIRST: offs/dinv for this node
    float di = 0.f;
    int start = 0, end = 0;
    if (node < N) {
        di = dinv[node];
        start = offs[node];
        end = offs[node + 1];
    }

    // stage weights (independent loads — fill the latency shadow)
    for (int i = tid; i < IN_DIM * HID_DIM; i += 256) W1s[i] = W1[i];
    for (int i = tid; i < HID_DIM * OUT_DIM; i += 256) W2s[i] = W2[i];
    if (tid < HID_DIM) b1s[tid] = b1[tid];

    // ---- gather phase ----
    float acc[8] = {0.f, 0.f, 0.f, 0.f, 0.f, 0.f, 0.f, 0.f};
    if (node < N) {                          // predicated, NOT return: barriers below
        const uint4* x2 = (const uint4*)xh;  // [N][2] uint4
        if (way == 0) {
            uint4 r = x2[(size_t)node * 2 + comp];
            const __half2* hp = (const __half2*)&r;
            #pragma unroll
            for (int c = 0; c < 4; ++c) {
                float2 f = __half22float2(hp[c]);
                acc[c * 2]     = di * f.x;
                acc[c * 2 + 1] = di * f.y;
            }
        }
        int j = start + way;
        for (; j + 8 < end; j += 16) {
            int s0 = csr[j], s1 = csr[j + 8];
            float w0 = dinv[s0], w1 = dinv[s1];
            uint4 r0 = x2[(size_t)s0 * 2 + comp];
            uint4 r1 = x2[(size_t)s1 * 2 + comp];
            const __half2* hp0 = (const __half2*)&r0;
            const __half2* hp1 = (const __half2*)&r1;
            #pragma unroll
            for (int c = 0; c < 4; ++c) {
                float2 f0 = __half22float2(hp0[c]);
                float2 f1 = __half22float2(hp1[c]);
                acc[c * 2]     += w0 * f0.x + w1 * f1.x;
                acc[c * 2 + 1] += w0 * f0.y + w1 * f1.y;
            }
        }
        if (j < end) {
            int s = csr[j];
            float w = dinv[s];
            uint4 r = x2[(size_t)s * 2 + comp];
            const __half2* hp = (const __half2*)&r;
            #pragma unroll
            for (int c = 0; c < 4; ++c) {
                float2 f = __half22float2(hp[c]);
                acc[c * 2]     += w * f.x;
                acc[c * 2 + 1] += w * f.y;
            }
        }
        // xor-reduce over way bits (lanes in each xor group share `node`)
        #pragma unroll
        for (int m = 1; m <= 4; m <<= 1) {
            #pragma unroll
            for (int c = 0; c < 8; ++c) acc[c] += __shfl_xor(acc[c], m, 64);
        }
    }
    if (way == 0) {   // both comps write; invalid nodes write zeros (di=0)
        #pragma unroll
        for (int c = 0; c < 8; ++c) aggs[nl * ASTR + comp * 8 + c] = di * acc[c];
    }
    __syncthreads();

    // ---- GEMM phase: thread = (node nl2, quarter-col q) ----
    int nl2 = tid >> 4, q = tid & 15;

    // GEMM1 + ReLU: hidden cols q*4 .. q*4+3
    float a1[4];
    #pragma unroll
    for (int c = 0; c < 4; ++c) a1[c] = b1s[q * 4 + c];
    #pragma unroll
    for (int k = 0; k < IN_DIM; ++k) {
        float a = aggs[nl2 * ASTR + k];
        float4 w = *(const float4*)&W1s[k * HID_DIM + q * 4];
        a1[0] += a * w.x; a1[1] += a * w.y; a1[2] += a * w.z; a1[3] += a * w.w;
    }
    *(float4*)&h1s[nl2 * H1S + q * 4] =
        make_float4(fmaxf(a1[0], 0.f), fmaxf(a1[1], 0.f),
                    fmaxf(a1[2], 0.f), fmaxf(a1[3], 0.f));
    __syncthreads();

    // GEMM2: out cols q*2, q*2+1 -> fp16 (one uint per thread; 16 consecutive
    // uints per node = 64 B coalesced store)
    float a2x = 0.f, a2y = 0.f;
    const float4* h1row = (const float4*)&h1s[nl2 * H1S];
    #pragma unroll
    for (int k4 = 0; k4 < 16; ++k4) {
        float4 hv = h1row[k4];
        const float* wb = &W2s[(k4 * 4) * OUT_DIM + q * 2];
        float2 w0 = *(const float2*)(wb);
        float2 w1 = *(const float2*)(wb + OUT_DIM);
        float2 w2 = *(const float2*)(wb + 2 * OUT_DIM);
        float2 w3 = *(const float2*)(wb + 3 * OUT_DIM);
        a2x += hv.x * w0.x + hv.y * w1.x + hv.z * w2.x + hv.w * w3.x;
        a2y += hv.x * w0.y + hv.y * w1.y + hv.z * w2.y + hv.w * w3.y;
    }
    int gn = blockIdx.x * 16 + nl2;
    if (gn < N) {
        __half2 p = __floats2half2_rn(a2x, a2y);
        ((unsigned int*)h2)[(size_t)gn * 16 + q] = *(unsigned int*)&p;
    }
}

// ---------------------------------------------------------------------------
// Layer-2 gather (r3/r6 form — measured in 128.9 config): 4 nodes per wave;
// 4 comps (uint4 = 8 fp16 ch of the 64 B row) x 4 edge-ways; 2 xor steps.
// out[i][c] = b2[c] + di*(di*h2[i][c] + sum_s dinv_s*h2[s][c])
// (r15's 2x8 remap regressed 128.9->131.9 — reverted; r4's variant also
// failed: the r3 gather layout is locally optimal for Poisson(16) degrees.)
// ---------------------------------------------------------------------------
__global__ __launch_bounds__(256, 8) void k_agg2(
    const __half* __restrict__ h2, const float* __restrict__ dinv,
    const int* __restrict__ offs, const unsigned short* __restrict__ csr,
    const float* __restrict__ b2, float* __restrict__ out, int N)
{
    int gtid = blockIdx.x * 256 + threadIdx.x;
    int lane = gtid & 63;
    int g = lane >> 4, sub = lane & 15;
    int comp = sub & 3, way = sub >> 2;           // 4 comps x 4 ways
    int node = (gtid >> 6) * 4 + g;
    if (node >= N) return;
    const uint4* h24 = (const uint4*)h2;
    float di = dinv[node];
    int start = offs[node], end = offs[node + 1];
    float acc[8] = {0.f, 0.f, 0.f, 0.f, 0.f, 0.f, 0.f, 0.f};
    if (way == 0) {
        uint4 r = h24[(size_t)node * 4 + comp];
        const __half2* hp = (const __half2*)&r;
        #pragma unroll
        for (int c = 0; c < 4; ++c) {
            float2 f = __half22float2(hp[c]);
            acc[c * 2]     = di * f.x;
            acc[c * 2 + 1] = di * f.y;
        }
    }
    int j = start + way;
    for (; j + 4 < end; j += 8) {
        int s0 = csr[j], s1 = csr[j + 4];
        float w0 = dinv[s0], w1 = dinv[s1];
        uint4 r0 = h24[(size_t)s0 * 4 + comp];
        uint4 r1 = h24[(size_t)s1 * 4 + comp];
        const __half2* hp0 = (const __half2*)&r0;
        const __half2* hp1 = (const __half2*)&r1;
        #pragma unroll
        for (int c = 0; c < 4; ++c) {
            float2 f0 = __half22float2(hp0[c]);
            float2 f1 = __half22float2(hp1[c]);
            acc[c * 2]     += w0 * f0.x + w1 * f1.x;
            acc[c * 2 + 1] += w0 * f0.y + w1 * f1.y;
        }
    }
    if (j < end) {
        int s = csr[j];
        float w = dinv[s];
        uint4 r = h24[(size_t)s * 4 + comp];
        const __half2* hp = (const __half2*)&r;
        #pragma unroll
        for (int c = 0; c < 4; ++c) {
            float2 f = __half22float2(hp[c]);
            acc[c * 2]     += w * f.x;
            acc[c * 2 + 1] += w * f.y;
        }
    }
    #pragma unroll
    for (int m = 4; m <= 8; m <<= 1) {
        #pragma unroll
        for (int c = 0; c < 8; ++c) acc[c] += __shfl_xor(acc[c], m, 64);
    }
    if (way == 0) {
        const float4* b24 = (const float4*)b2;
        float4 bb0 = b24[comp * 2], bb1 = b24[comp * 2 + 1];
        float4* out4 = (float4*)out;
        out4[(size_t)node * 8 + comp * 2 + 0] =
            make_float4(di * acc[0] + bb0.x, di * acc[1] + bb0.y,
                        di * acc[2] + bb0.z, di * acc[3] + bb0.w);
        out4[(size_t)node * 8 + comp * 2 + 1] =
            make_float4(di * acc[4] + bb1.x, di * acc[5] + bb1.y,
                        di * acc[6] + bb1.z, di * acc[7] + bb1.w);
    }
}

extern "C" void kernel_launch(void* const* d_in, const int* in_sizes, int n_in,
                              void* d_out, int out_size, void* d_ws, size_t ws_size,
                              hipStream_t stream) {
    const float* x     = (const float*)d_in[0];
    const void*  edges = d_in[1];
    const float* W1    = (const float*)d_in[2];
    const float* b1    = (const float*)d_in[3];
    const float* W2    = (const float*)d_in[4];
    const float* b2    = (const float*)d_in[5];
    float* out = (float*)d_out;

    const int       N = in_sizes[0] / IN_DIM;   // 50000 (fits u16)
    const long long E = in_sizes[1] / 2;        // 800000
    const int    NBUK = (N + 255) >> 8;         // 196 coarse buckets (<=256)
    const int   NBLKA = (int)((E + EPB - 1) / EPB);

    // ws layout: csr [E u16, pad to 16B] | gpart [NBUK*CAP u32] | xh [16N half]
    // | h2 [32N half] | dinv [N f] | offs [N+1] | gcur [NBUK]
    unsigned short* csr   = (unsigned short*)d_ws;
    unsigned int*   gpart = (unsigned int*)(csr + ((E + 7) & ~7LL));
    __half* xh       = (__half*)(gpart + (size_t)NBUK * CAP);
    __half* h2       = (__half*)(xh + (size_t)IN_DIM * N);
    float*  dinv     = (float*)(h2 + (size_t)OUT_DIM * N);
    int*    offs     = (int*)(dinv + N);
    int*    gcur     = offs + N + 1;

    const int B = 256;
    hipMemsetAsync(gcur, 0, (size_t)NBUK * sizeof(int), stream);
    k_partA<<<NBLKA + CONVB, PAT, 0, stream>>>(edges, gcur, gpart, NBUK, E,
                                               x, xh, (long long)N * IN_DIM, NBLKA);
    k_partB<<<NBUK, PBT, 0, stream>>>(gcur, gpart, csr, offs, dinv, NBUK, N);

    // fused gather + GEMMs: 16 nodes per 256-thread block
    k_agg1g<<<(N + 15) / 16, B, 0, stream>>>(xh, dinv, offs, csr,
                                             W1, b1, W2, h2, N);
    k_agg2<<<(N + 15) / 16, B, 0, stream>>>(h2, dinv, offs, csr, b2, out, N);
}